// Round 4
// baseline (222.078 us; speedup 1.0000x reference)
//
#include <hip/hip_runtime.h>
#include <stdint.h>

#define DEV __device__ __forceinline__

typedef __attribute__((ext_vector_type(4))) float f32x4;
typedef __attribute__((ext_vector_type(8))) __bf16 bf16x8;
typedef __attribute__((ext_vector_type(8))) unsigned short ushort8;

DEV unsigned short f2bf(float f) {
    union { float f; unsigned int u; } v; v.f = f;
    unsigned int r = v.u + 0x7FFFu + ((v.u >> 16) & 1u);
    return (unsigned short)(r >> 16);
}
DEV float bf2f(unsigned short u) {
    union { unsigned int u; float f; } v; v.u = ((unsigned int)u) << 16;
    return v.f;
}
// XOR-swizzle a linear LDS byte offset (128B rows): byte ^= ((row&7)<<4)
DEV int swz(int o) { return o ^ ((o >> 3) & 0x70); }

DEV void gload_lds16(const void* gptr, void* lptr) {
    __builtin_amdgcn_global_load_lds(
        (const __attribute__((address_space(1))) unsigned int*)gptr,
        (__attribute__((address_space(3))) unsigned int*)lptr, 16, 0, 0);
}

// ---------------- fp32 -> bf16 convert of q,k,v ----------------
__global__ void k_convert(const float* __restrict__ q, const float* __restrict__ k,
                          const float* __restrict__ v, unsigned short* __restrict__ qb,
                          unsigned short* __restrict__ kb, unsigned short* __restrict__ vb) {
    const int z = blockIdx.z;
    const float* src = z == 0 ? q : (z == 1 ? k : v);
    unsigned short* dst = z == 0 ? qb : (z == 1 ? kb : vb);
    const size_t idx = ((size_t)blockIdx.x * 256 + threadIdx.x) * 8;
    f32x4 a = *(const f32x4*)(src + idx);
    f32x4 b = *(const f32x4*)(src + idx + 4);
    ushort8 o;
    o[0] = f2bf(a[0]); o[1] = f2bf(a[1]); o[2] = f2bf(a[2]); o[3] = f2bf(a[3]);
    o[4] = f2bf(b[0]); o[5] = f2bf(b[1]); o[6] = f2bf(b[2]); o[7] = f2bf(b[3]);
    *(ushort8*)(dst + idx) = o;
}

// ---------------- W (fp32 [k][n]) -> Wt (bf16 [n][k]) ----------------
__global__ void k_convw(const float* __restrict__ Wq, const float* __restrict__ Wk,
                        const float* __restrict__ Wv, unsigned short* __restrict__ wt) {
    __shared__ float tile[64 * 65];
    const int z = blockIdx.z;
    const float* W = z == 0 ? Wq : (z == 1 ? Wk : Wv);
    unsigned short* dst = wt + (size_t)z * 1048576;
    const int k0 = blockIdx.x * 64, n0 = blockIdx.y * 64;
    const int t = threadIdx.x;
#pragma unroll
    for (int i = 0; i < 4; i++) {
        const int idx = i * 256 + t;
        const int row = idx >> 4, c4 = (idx & 15) * 4;
        f32x4 val = *(const f32x4*)(W + (size_t)(k0 + row) * 1024 + n0 + c4);
#pragma unroll
        for (int j = 0; j < 4; j++) tile[row * 65 + c4 + j] = val[j];
    }
    __syncthreads();
#pragma unroll
    for (int i = 0; i < 2; i++) {
        const int idx = i * 256 + t;
        const int nrow = idx >> 3, c8 = (idx & 7) * 8;
        ushort8 o;
#pragma unroll
        for (int j = 0; j < 8; j++) o[j] = f2bf(tile[(c8 + j) * 65 + nrow]);
        *(ushort8*)(dst + (size_t)(n0 + nrow) * 1024 + k0 + c8) = o;
    }
}

// ---------------- projection GEMM: C = A(4096x1024) * Wt^T + bias ----------------
__global__ __launch_bounds__(256) void k_proj(
    const unsigned short* __restrict__ qb, const unsigned short* __restrict__ kb,
    const unsigned short* __restrict__ vb, const unsigned short* __restrict__ wt,
    const float* __restrict__ bq, const float* __restrict__ bk, const float* __restrict__ bv,
    unsigned short* __restrict__ qh, unsigned short* __restrict__ kh,
    unsigned short* __restrict__ vh) {
    const int z = blockIdx.z;
    const unsigned short* A  = z == 0 ? qb : (z == 1 ? kb : vb);
    const unsigned short* Bt = wt + (size_t)z * 1048576;
    const float* bias = z == 0 ? bq : (z == 1 ? bk : bv);
    unsigned short* outp = z == 0 ? qh : (z == 1 ? kh : vh);
    // z==0: fold 1/sqrt(dh) * log2(e) so attention softmax runs in exp2 domain
    const float scale = z == 0 ? 0.18033688011112042f : 1.0f;

    __shared__ unsigned short sA[128 * 64];
    __shared__ unsigned short sB[128 * 64];

    const int tid = threadIdx.x;
    const int w = tid >> 6, lane = tid & 63;
    const int c = lane & 15, gq = lane >> 4;
    const int wrow = w >> 1, wcol = w & 1;
    const int m0 = blockIdx.y * 128, n0 = blockIdx.x * 128;
    const int lr = lane >> 3;
    const int lcs = ((lane & 7) ^ (lane >> 3)) * 8;

    f32x4 acc[4][4] = {};

    for (int kt = 0; kt < 16; kt++) {
        __syncthreads();
        const int kb0 = kt * 64;
#pragma unroll
        for (int i = 0; i < 4; i++) {
            const int rbase = w * 32 + i * 8;
            gload_lds16(A  + (size_t)(m0 + rbase + lr) * 1024 + kb0 + lcs,
                        (char*)sA + rbase * 128);
            gload_lds16(Bt + (size_t)(n0 + rbase + lr) * 1024 + kb0 + lcs,
                        (char*)sB + rbase * 128);
        }
        __syncthreads();
#pragma unroll
        for (int kk = 0; kk < 2; kk++) {
            bf16x8 af[4], bfr[4];
#pragma unroll
            for (int i = 0; i < 4; i++) {
                af[i]  = *(const bf16x8*)((char*)sA +
                          swz((wrow * 64 + i * 16 + c) * 128 + kk * 64 + gq * 16));
                bfr[i] = *(const bf16x8*)((char*)sB +
                          swz((wcol * 64 + i * 16 + c) * 128 + kk * 64 + gq * 16));
            }
#pragma unroll
            for (int mi = 0; mi < 4; mi++)
#pragma unroll
                for (int ni = 0; ni < 4; ni++)
                    acc[mi][ni] = __builtin_amdgcn_mfma_f32_16x16x32_bf16(
                        af[mi], bfr[ni], acc[mi][ni], 0, 0, 0);
        }
    }

    float bvals[4];
#pragma unroll
    for (int ni = 0; ni < 4; ni++) bvals[ni] = bias[n0 + wcol * 64 + ni * 16 + c];

#pragma unroll
    for (int mi = 0; mi < 4; mi++)
#pragma unroll
        for (int ni = 0; ni < 4; ni++) {
            const int n = n0 + wcol * 64 + ni * 16 + c;
            const int head = n >> 6, d = n & 63;
#pragma unroll
            for (int r = 0; r < 4; r++) {
                const int m = m0 + wrow * 64 + mi * 16 + gq * 4 + r;
                const int bb = m >> 10, s = m & 1023;
                const float val = (acc[mi][ni][r] + bvals[ni]) * scale;
                outp[(size_t)((head << 2) + bb) * 65536 + (size_t)s * 64 + d] = f2bf(val);
            }
        }
}

// ---------------- vh [hb][s][d] -> vt [hb][d][s]  (+ column-mean atomics) ----------------
__global__ void k_trv(const unsigned short* __restrict__ vh, unsigned short* __restrict__ vt,
                      float* __restrict__ vmean) {
    __shared__ unsigned int tile[64 * 65];
    const int hb = blockIdx.y, s0 = blockIdx.x * 64;
    const int t = threadIdx.x;
#pragma unroll
    for (int it = 0; it < 2; it++) {
        const int idx = it * 256 + t;
        const int row = idx >> 3, c8 = (idx & 7) * 8;
        ushort8 val = *(const ushort8*)(vh + (size_t)hb * 65536 + (size_t)(s0 + row) * 64 + c8);
#pragma unroll
        for (int j = 0; j < 8; j++) tile[row * 65 + c8 + j] = val[j];
    }
    __syncthreads();
#pragma unroll
    for (int it = 0; it < 2; it++) {
        const int idx = it * 256 + t;
        const int d = idx >> 3, s8 = (idx & 7) * 8;
        ushort8 o;
#pragma unroll
        for (int j = 0; j < 8; j++) o[j] = (unsigned short)tile[(s8 + j) * 65 + d];
        *(ushort8*)(vt + (size_t)hb * 65536 + (size_t)d * 1024 + s0 + s8) = o;
    }
    if (t < 64) {   // per-block partial column sum (fully-masked-row fallback)
        float sum = 0.f;
        for (int s = 0; s < 64; s++) sum += bf2f((unsigned short)tile[s * 65 + t]);
        atomicAdd(&vmean[hb * 64 + t], sum * (1.0f / 1024.0f));
    }
}

// ---------------- flash attention, split-KV ----------------
// grid (40, 64): idx -> (qt, chunk); chunk covers KV tiles [4c, min(4c+4, qt+1)).
// 256 threads = 4 waves, wave w owns q-rows [qt*64+w*16, +16).
// Softmax in exp2/log2 domain (log2e folded into q scale).
__global__ __launch_bounds__(256) void k_attn(
    const unsigned short* __restrict__ qh, const unsigned short* __restrict__ kh,
    const unsigned short* __restrict__ vt, const int* __restrict__ mask,
    const float* __restrict__ vmean, float* __restrict__ out,
    char* __restrict__ part) {
    __shared__ unsigned short sK[2][64 * 64];
    __shared__ unsigned short sV[2][64 * 64];   // V^T tiles: [d][kv]
    __shared__ unsigned short sP[4 * 16 * 64];

    const int idx = blockIdx.x, hb = blockIdx.y;
    int qt, ch, nch;
    if (idx < 4)       { qt = idx;                 ch = 0;             nch = 1; }
    else if (idx < 12) { qt = 4 + ((idx - 4) >> 1);  ch = (idx - 4) & 1;  nch = 2; }
    else if (idx < 24) { int r = idx - 12; qt = 8 + r / 3; ch = r % 3;   nch = 3; }
    else               { qt = 12 + ((idx - 24) >> 2); ch = (idx - 24) & 3; nch = 4; }
    const int t0 = ch * 4;
    const int t1 = min(t0 + 4, qt + 1);

    const int tid = threadIdx.x;
    const int w = tid >> 6, lane = tid & 63;
    const int c = lane & 15, g = lane >> 4;
    const int q0 = qt * 64 + w * 16;
    const size_t hboff = (size_t)hb * 65536;
    const int* mp = mask + hb * 1024;

    bf16x8 aq[2];
#pragma unroll
    for (int kk = 0; kk < 2; kk++)
        aq[kk] = *(const bf16x8*)(qh + hboff + (size_t)(q0 + c) * 64 + kk * 32 + g * 8);

    f32x4 oacc[4] = {};
    float lsum[4] = {0.f, 0.f, 0.f, 0.f};
    float mrow[4] = {-1e30f, -1e30f, -1e30f, -1e30f};
    unsigned short* pw = sP + w * 1024;

    const int srow = tid >> 3, sch = tid & 7;
    const int ssc = (sch ^ (srow & 7)) * 8;          // pre-swizzled source col

    auto stage = [&](int t, int buf) {
        const int kv0 = t * 64;
#pragma unroll
        for (int i = 0; i < 2; i++) {
            const int row = i * 32 + srow;
            gload_lds16(kh + hboff + (size_t)(kv0 + row) * 64 + ssc,
                        (char*)sK[buf] + row * 128 + sch * 16);
        }
#pragma unroll
        for (int i = 0; i < 2; i++) {
            const int row = i * 32 + srow;               // row = d
            gload_lds16(vt + hboff + (size_t)row * 1024 + kv0 + ssc,
                        (char*)sV[buf] + row * 128 + sch * 16);
        }
    };

    stage(t0, 0);
    for (int t = t0; t < t1; t++) {
        const int cur = (t - t0) & 1;
        if (t + 1 < t1) {
            stage(t + 1, cur ^ 1);
            asm volatile("s_waitcnt vmcnt(4)" ::: "memory");
        } else {
            asm volatile("s_waitcnt vmcnt(0)" ::: "memory");
        }
        __builtin_amdgcn_s_barrier();
        __builtin_amdgcn_sched_barrier(0);

        const int kv0 = t * 64;
        const bool diag = (t == qt);
        const unsigned short* sKc = sK[cur];
        const unsigned short* sVc = sV[cur];

        // S = Q K^T
        f32x4 sacc[4] = {};
#pragma unroll
        for (int ns = 0; ns < 4; ns++) {
            const int kvl = ns * 16 + c;
#pragma unroll
            for (int kk = 0; kk < 2; kk++) {
                bf16x8 bk = *(const bf16x8*)((char*)sKc + swz(kvl * 128 + kk * 64 + g * 16));
                sacc[ns] = __builtin_amdgcn_mfma_f32_16x16x32_bf16(aq[kk], bk, sacc[ns], 0, 0, 0);
            }
        }
        // mask + online softmax (log2 domain)
        float sv[4][4];
#pragma unroll
        for (int ns = 0; ns < 4; ns++) {
            const int kvg = kv0 + ns * 16 + c;
            const int mv = mp[kvg];
#pragma unroll
            for (int r = 0; r < 4; r++) {
                const bool ok = (mv != 0) && (!diag || kvg <= q0 + g * 4 + r);
                sv[ns][r] = ok ? sacc[ns][r] : -1e30f;
            }
        }
#pragma unroll
        for (int r = 0; r < 4; r++) {
            float vmax = fmaxf(fmaxf(sv[0][r], sv[1][r]), fmaxf(sv[2][r], sv[3][r]));
            vmax = fmaxf(vmax, __shfl_xor(vmax, 1, 64));
            vmax = fmaxf(vmax, __shfl_xor(vmax, 2, 64));
            vmax = fmaxf(vmax, __shfl_xor(vmax, 4, 64));
            vmax = fmaxf(vmax, __shfl_xor(vmax, 8, 64));
            const float mnew = fmaxf(mrow[r], vmax);
            const float alpha = exp2f(mrow[r] - mnew);
            mrow[r] = mnew;
            float rs = 0.f;
            const int ql = g * 4 + r;
#pragma unroll
            for (int ns = 0; ns < 4; ns++) {
                const float pv = exp2f(sv[ns][r] - mnew);
                rs += pv;
                *(unsigned short*)((char*)pw + swz(ql * 128 + (ns * 16 + c) * 2)) = f2bf(pv);
            }
            rs += __shfl_xor(rs, 1, 64);
            rs += __shfl_xor(rs, 2, 64);
            rs += __shfl_xor(rs, 4, 64);
            rs += __shfl_xor(rs, 8, 64);
            lsum[r] = lsum[r] * alpha + rs;
#pragma unroll
            for (int nd = 0; nd < 4; nd++) oacc[nd][r] *= alpha;
        }
        asm volatile("s_waitcnt lgkmcnt(0)" ::: "memory");
        // O += P V
#pragma unroll
        for (int ks = 0; ks < 2; ks++) {
            const bf16x8 ap = *(const bf16x8*)((char*)pw + swz(c * 128 + ks * 64 + g * 16));
#pragma unroll
            for (int nd = 0; nd < 4; nd++) {
                const int d = nd * 16 + c;
                const bf16x8 bvv = *(const bf16x8*)((char*)sVc + swz(d * 128 + ks * 64 + g * 16));
                oacc[nd] = __builtin_amdgcn_mfma_f32_16x16x32_bf16(ap, bvv, oacc[nd], 0, 0, 0);
            }
        }
        __builtin_amdgcn_sched_barrier(0);
        __builtin_amdgcn_s_barrier();      // LDS reads done before next stage overwrites
        __builtin_amdgcn_sched_barrier(0);
    }

    if (nch == 1) {
        const int bidx = hb & 3, head = hb >> 2;
#pragma unroll
        for (int nd = 0; nd < 4; nd++)
#pragma unroll
            for (int r = 0; r < 4; r++) {
                const int s = q0 + g * 4 + r;
                const int dcol = nd * 16 + c;
                const float val = (mrow[r] < -5e29f) ? vmean[hb * 64 + dcol]
                                                     : oacc[nd][r] / lsum[r];
                out[(size_t)bidx * 1048576 + (size_t)s * 1024 + head * 64 + dcol] = val;
            }
    } else {
        // partial: bf16 O~ [64][64] + f32 m[64] + f32 l[64]  (slot = idx-4)
        char* sp = part + ((size_t)hb * 36 + (idx - 4)) * 8704;
        unsigned short* op = (unsigned short*)sp;
#pragma unroll
        for (int nd = 0; nd < 4; nd++)
#pragma unroll
            for (int r = 0; r < 4; r++)
                op[(w * 16 + g * 4 + r) * 64 + nd * 16 + c] = f2bf(oacc[nd][r]);
        if (c == 0) {
            float* mo = (float*)(sp + 8192);
            float* lo = (float*)(sp + 8448);
#pragma unroll
            for (int r = 0; r < 4; r++) {
                mo[w * 16 + g * 4 + r] = mrow[r];
                lo[w * 16 + g * 4 + r] = lsum[r];
            }
        }
    }
}

// ---------------- combine partials for qt >= 4 ----------------
__global__ __launch_bounds__(256) void k_combine(
    const char* __restrict__ part, const float* __restrict__ vmean,
    float* __restrict__ out) {
    const int qt = 4 + blockIdx.x, hb = blockIdx.y;
    int nch, base;
    if (qt < 8)       { nch = 2; base = (qt - 4) * 2; }
    else if (qt < 12) { nch = 3; base = 8 + (qt - 8) * 3; }
    else              { nch = 4; base = 20 + (qt - 12) * 4; }
    const int t = threadIdx.x;
    const int row = t >> 2, d0 = (t & 3) * 16;
    const char* sp0 = part + ((size_t)hb * 36 + base) * 8704;

    float mi[4], li[4];
    float m = -1e30f;
#pragma unroll
    for (int i = 0; i < 4; i++)
        if (i < nch) {
            const char* sp = sp0 + (size_t)i * 8704;
            mi[i] = ((const float*)(sp + 8192))[row];
            li[i] = ((const float*)(sp + 8448))[row];
            m = fmaxf(m, mi[i]);
        }
    float L = 0.f;
    float o[16];
#pragma unroll
    for (int j = 0; j < 16; j++) o[j] = 0.f;
#pragma unroll
    for (int i = 0; i < 4; i++)
        if (i < nch) {
            const float wgt = exp2f(mi[i] - m);
            L += wgt * li[i];
            const unsigned short* op =
                (const unsigned short*)(sp0 + (size_t)i * 8704) + row * 64 + d0;
            ushort8 a = *(const ushort8*)op;
            ushort8 b = *(const ushort8*)(op + 8);
#pragma unroll
            for (int j = 0; j < 8; j++) {
                o[j]     += wgt * bf2f(a[j]);
                o[8 + j] += wgt * bf2f(b[j]);
            }
        }
    const int bidx = hb & 3, head = hb >> 2;
    float* dst = out + (size_t)bidx * 1048576 + (size_t)(qt * 64 + row) * 1024 + head * 64 + d0;
    if (L > 0.f) {
        const float inv = 1.0f / L;
#pragma unroll
        for (int j = 0; j < 16; j++) dst[j] = o[j] * inv;
    } else {
#pragma unroll
        for (int j = 0; j < 16; j++) dst[j] = vmean[hb * 64 + d0 + j];
    }
}

extern "C" void kernel_launch(void* const* d_in, const int* in_sizes, int n_in,
                              void* d_out, int out_size, void* d_ws, size_t ws_size,
                              hipStream_t stream) {
    const float* q  = (const float*)d_in[0];
    const float* k  = (const float*)d_in[1];
    const float* v  = (const float*)d_in[2];
    const int* mask = (const int*)d_in[3];
    const float* Wq = (const float*)d_in[4];
    const float* bq = (const float*)d_in[5];
    const float* Wk = (const float*)d_in[6];
    const float* bk = (const float*)d_in[7];
    const float* Wv = (const float*)d_in[8];
    const float* bv = (const float*)d_in[9];
    float* out = (float*)d_out;

    unsigned short* qb = (unsigned short*)d_ws;
    unsigned short* kb = qb + 4194304;
    unsigned short* vb = kb + 4194304;
    unsigned short* wt = vb + 4194304;     // 3 * 1048576
    unsigned short* qh = wt + 3 * 1048576;
    unsigned short* kh = qh + 4194304;
    unsigned short* vh = kh + 4194304;
    unsigned short* vt = vh + 4194304;
    float* vmean = (float*)(vt + 4194304); // 64*64 floats
    char* part = (char*)qb;                // 20.1 MB, aliases qb/kb/vb (dead after k_proj)

    k_convert<<<dim3(2048, 1, 3), 256, 0, stream>>>(q, k, v, qb, kb, vb);
    k_convw<<<dim3(16, 16, 3), 256, 0, stream>>>(Wq, Wk, Wv, wt);
    k_proj<<<dim3(8, 32, 3), 256, 0, stream>>>(qb, kb, vb, wt, bq, bk, bv, qh, kh, vh);
    hipMemsetAsync(vmean, 0, 64 * 64 * sizeof(float), stream);
    k_trv<<<dim3(16, 64), 256, 0, stream>>>(vh, vt, vmean);
    k_attn<<<dim3(40, 64), 256, 0, stream>>>(qh, kh, vt, mask, vmean, out, part);
    k_combine<<<dim3(12, 64), 256, 0, stream>>>(part, vmean, out);
}